// Round 3
// baseline (355.785 us; speedup 1.0000x reference)
//
#include <hip/hip_runtime.h>
#include <math.h>

// Problem sizes (fixed by setup_inputs)
constexpr int N_V  = 16384;       // original vertices
constexpr int N_F  = 16384;       // original faces (targets for fwd)
constexpr int G_F  = 8192;        // simplified faces (queries for fwd)
constexpr int NS   = 16;          // samples per face
constexpr int NPTS = G_F * NS;    // 131072 sample points (queries for rev)

constexpr int MB = 4;             // 32-row query blocks per wave (128 queries/wave)

typedef _Float16 half8 __attribute__((ext_vector_type(8)));
typedef float    f32x16 __attribute__((ext_vector_type(16)));

// ---------------- workspace layout (float4 units first, 16B aligned) ----------
constexpr int F4_ACC   = 0;                    // 1  float4: accumulators
constexpr int F4_SB    = 1;                    // [G_F]  simp barycenters x,y,z,|b|^2
constexpr int F4_PTS   = F4_SB + G_F;          // [NPTS] sample points    x,y,z,|p|^2
constexpr int F4_PKV   = F4_PTS + NPTS;        // packed verts: 512 tiles * 64 * 16B = 32768 f4
constexpr int F4_PKO   = F4_PKV + 32768;       // packed obary: 32768 f4
constexpr int F4_TOTAL = F4_PKO + 32768;
constexpr int WS_MINF  = F4_TOTAL * 4;         // [G_F]  fwd min d^2 (uint bits)
constexpr int WS_MINR  = WS_MINF + G_F;        // [NPTS] rev min d^2 (uint bits)

__global__ void k_init(unsigned int* __restrict__ ws) {
  int i = blockIdx.x * blockDim.x + threadIdx.x;
  if (i < 4) ws[i] = 0u;                          // float accumulators (0.0f)
  if (i < G_F) ws[WS_MINF + i] = 0x7f800000u;     // +inf
  ws[WS_MINR + i] = 0x7f800000u;                  // +inf (grid covers NPTS exactly)
}

// Pack one target (x,y,z,sq) into the B-fragment-order array.
// Column K-layout (K=16): k0-3 = hi(-2x,-2y,-2z,|v|^2), k4-7 = lo(residuals),
// k8-11 = hi again, k12-15 = 0.  Per-lane frag order: half0 lane n -> (hi,lo),
// half1 lane n -> (hi, 0).
__device__ __forceinline__ void pack_target(float x, float y, float z, float sq,
                                            half8* __restrict__ pk, int tile, int n) {
  float ax = -2.0f*x, ay = -2.0f*y, az = -2.0f*z;
  _Float16 hx = (_Float16)ax, hy = (_Float16)ay, hz = (_Float16)az, hw = (_Float16)sq;
  _Float16 lx = (_Float16)(ax - (float)hx), ly = (_Float16)(ay - (float)hy);
  _Float16 lz = (_Float16)(az - (float)hz), lw = (_Float16)(sq - (float)hw);
  half8 h0; h0[0]=hx; h0[1]=hy; h0[2]=hz; h0[3]=hw; h0[4]=lx; h0[5]=ly; h0[6]=lz; h0[7]=lw;
  half8 h1; h1[0]=hx; h1[1]=hy; h1[2]=hz; h1[3]=hw;
  h1[4]=(_Float16)0.0f; h1[5]=(_Float16)0.0f; h1[6]=(_Float16)0.0f; h1[7]=(_Float16)0.0f;
  pk[(size_t)tile*64 + n]      = h0;
  pk[(size_t)tile*64 + 32 + n] = h1;
}

__global__ void k_pack_verts(const float* __restrict__ ov, half8* __restrict__ pk) {
  int i = blockIdx.x * blockDim.x + threadIdx.x;
  if (i >= N_V) return;
  float x = ov[3*i], y = ov[3*i+1], z = ov[3*i+2];
  pack_target(x, y, z, fmaf(x, x, fmaf(y, y, z*z)), pk, i >> 5, i & 31);
}

__global__ void k_obary_pack(const float* __restrict__ ov, const int* __restrict__ of,
                             half8* __restrict__ pk) {
  int i = blockIdx.x * blockDim.x + threadIdx.x;
  if (i >= N_F) return;
  int a = of[3*i], b = of[3*i+1], c = of[3*i+2];
  float x = (ov[3*a] + ov[3*b] + ov[3*c]) * (1.0f/3.0f);
  float y = (ov[3*a+1] + ov[3*b+1] + ov[3*c+1]) * (1.0f/3.0f);
  float z = (ov[3*a+2] + ov[3*b+2] + ov[3*c+2]) * (1.0f/3.0f);
  pack_target(x, y, z, fmaf(x, x, fmaf(y, y, z*z)), pk, i >> 5, i & 31);
}

__global__ void k_sbary(const float* __restrict__ sv, const int* __restrict__ sf,
                        float4* __restrict__ b4) {
  int i = blockIdx.x * blockDim.x + threadIdx.x;
  if (i >= G_F) return;
  int a = sf[3*i], b = sf[3*i+1], c = sf[3*i+2];
  float x = (sv[3*a] + sv[3*b] + sv[3*c]) * (1.0f/3.0f);
  float y = (sv[3*a+1] + sv[3*b+1] + sv[3*c+1]) * (1.0f/3.0f);
  float z = (sv[3*a+2] + sv[3*b+2] + sv[3*c+2]) * (1.0f/3.0f);
  b4[i] = make_float4(x, y, z, fmaf(x, x, fmaf(y, y, z*z)));
}

__global__ void k_pts(const float* __restrict__ sv, const int* __restrict__ sf,
                      const float* __restrict__ r1, const float* __restrict__ r2,
                      float4* __restrict__ p4) {
  int i = blockIdx.x * blockDim.x + threadIdx.x;
  if (i >= NPTS) return;
  int g = i >> 4;
  int a = sf[3*g], b = sf[3*g+1], c = sf[3*g+2];
  float sr = sqrtf(r1[i]);
  float u = 1.0f - sr;
  float v = sr * (1.0f - r2[i]);
  float w = sr * r2[i];
  float px = u*sv[3*a]   + v*sv[3*b]   + w*sv[3*c];
  float py = u*sv[3*a+1] + v*sv[3*b+1] + w*sv[3*c+1];
  float pz = u*sv[3*a+2] + v*sv[3*b+2] + w*sv[3*c+2];
  p4[i] = make_float4(px, py, pz, fmaf(px, px, fmaf(py, py, pz*pz)));
}

// MFMA min-distance kernel.  Each wave owns 128 queries (MB=4 blocks of 32 rows)
// and sweeps tile chunk [blockIdx.y*tiles, +tiles) of 32-target B-tiles.
// d^2_partial(q,t) = -2 q.t + |t|^2 computed by ONE v_mfma_f32_32x32x16_f16 per
// (32q x 32t) tile via 2-term f16 splitting; |q|^2 folded after the min.
__global__ __launch_bounds__(256) void k_min(const float4* __restrict__ q4,
                                             const half8* __restrict__ pk,
                                             unsigned int* __restrict__ minU,
                                             int tiles) {
  int lane  = threadIdx.x & 63;
  int wave  = threadIdx.x >> 6;
  int half_ = lane >> 5;
  int m     = lane & 31;
  int group = blockIdx.x * 4 + wave;
  int qbase = group * (32 * MB);
  int t0 = blockIdx.y * tiles, t1 = t0 + tiles;

  // Build A fragments: A[m=lane&31][k=(lane>>5)*8+j]
  // half0: (p_hi,1, p_hi,1)   half1: (p_lo,0, 0,0,0,0)
  half8 afrag[MB];
  for (int mb = 0; mb < MB; ++mb) {
    float4 q = q4[qbase + mb*32 + m];
    _Float16 hx = (_Float16)q.x, hy = (_Float16)q.y, hz = (_Float16)q.z;
    half8 a;
    if (half_ == 0) {
      a[0]=hx; a[1]=hy; a[2]=hz; a[3]=(_Float16)1.0f;
      a[4]=hx; a[5]=hy; a[6]=hz; a[7]=(_Float16)1.0f;
    } else {
      a[0]=(_Float16)(q.x-(float)hx); a[1]=(_Float16)(q.y-(float)hy);
      a[2]=(_Float16)(q.z-(float)hz); a[3]=(_Float16)0.0f;
      a[4]=(_Float16)0.0f; a[5]=(_Float16)0.0f; a[6]=(_Float16)0.0f; a[7]=(_Float16)0.0f;
    }
    afrag[mb] = a;
  }

  f32x16 zero;
  #pragma unroll
  for (int r = 0; r < 16; ++r) zero[r] = 0.0f;

  float inf = __uint_as_float(0x7f800000u);
  float rm[MB][16];
  #pragma unroll
  for (int mb = 0; mb < MB; ++mb)
    #pragma unroll
    for (int r = 0; r < 16; ++r) rm[mb][r] = inf;

  half8 bf = pk[(size_t)t0*64 + lane];
  for (int t = t0; t < t1; ++t) {
    half8 cur = bf;
    if (t + 1 < t1) bf = pk[(size_t)(t+1)*64 + lane];   // prefetch next tile
    #pragma unroll
    for (int mb = 0; mb < MB; ++mb) {
      f32x16 d = __builtin_amdgcn_mfma_f32_32x32x16_f16(afrag[mb], cur, zero, 0, 0, 0);
      #pragma unroll
      for (int r = 0; r < 16; ++r) rm[mb][r] = fminf(rm[mb][r], d[r]);
    }
  }

  // min across the 32 target-columns (col = lane&31), then combine k-chunks.
  // C/D: col=lane&31, row=(reg&3)+8*(reg>>2)+4*(lane>>5)
  for (int mb = 0; mb < MB; ++mb) {
    #pragma unroll
    for (int r = 0; r < 16; ++r) {
      float v = rm[mb][r];
      v = fminf(v, __shfl_xor(v, 1, 64));
      v = fminf(v, __shfl_xor(v, 2, 64));
      v = fminf(v, __shfl_xor(v, 4, 64));
      v = fminf(v, __shfl_xor(v, 8, 64));
      v = fminf(v, __shfl_xor(v, 16, 64));
      if (m == 0) {
        int row  = (r & 3) + 8*(r >> 2) + 4*half_;
        int pidx = qbase + mb*32 + row;
        float d2 = fmaxf(q4[pidx].w + v, 0.0f);
        atomicMin(&minU[pidx], __float_as_uint(d2));
      }
    }
  }
}

__device__ __forceinline__ float waveSum(float v) {
  #pragma unroll
  for (int o = 32; o > 0; o >>= 1) v += __shfl_down(v, o, 64);
  return v;
}
__device__ __forceinline__ float waveMax(float v) {
  #pragma unroll
  for (int o = 32; o > 0; o >>= 1) v = fmaxf(v, __shfl_down(v, o, 64));
  return v;
}

__global__ void k_reduce(const float* __restrict__ probs, const float* __restrict__ minf,
                         const float* __restrict__ minr, float* __restrict__ acc) {
  int tid = blockIdx.x * blockDim.x + threadIdx.x;
  int stride = gridDim.x * blockDim.x;
  float sf = 0.0f, sr = 0.0f, mx = 0.0f;
  for (int i = tid; i < NPTS; i += stride) {
    float d = sqrtf(fmaxf(minr[i], 1e-12f));
    sr = fmaf(probs[i >> 4], d, sr);
    mx = fmaxf(mx, d);
    if (i < G_F) {
      float df = sqrtf(fmaxf(minf[i], 1e-12f));
      sf = fmaf(probs[i], df, sf);
      sf = fmaf(1e-4f, 1.0f - probs[i], sf);
    }
  }
  __shared__ float lf[4], lr[4], lm[4];
  int lane = threadIdx.x & 63, wid = threadIdx.x >> 6;
  sf = waveSum(sf); sr = waveSum(sr); mx = waveMax(mx);
  if (lane == 0) { lf[wid] = sf; lr[wid] = sr; lm[wid] = mx; }
  __syncthreads();
  if (wid == 0) {
    float a = (lane < 4) ? lf[lane] : 0.0f;
    float b = (lane < 4) ? lr[lane] : 0.0f;
    float c = (lane < 4) ? lm[lane] : 0.0f;
    a = waveSum(a); b = waveSum(b); c = waveMax(c);
    if (lane == 0) {
      atomicAdd(&acc[0], a);
      atomicAdd(&acc[1], b);
      atomicMax((unsigned int*)&acc[2], __float_as_uint(c));
    }
  }
}

__global__ void k_final(const float* __restrict__ acc, float* __restrict__ out) {
  float maxd = acc[2] + 1e-8f;
  out[0] = acc[0] + acc[1] * 0.1f / maxd;
}

extern "C" void kernel_launch(void* const* d_in, const int* in_sizes, int n_in,
                              void* d_out, int out_size, void* d_ws, size_t ws_size,
                              hipStream_t stream) {
  const float* ov    = (const float*)d_in[0];
  const int*   of    = (const int*)  d_in[1];
  const float* sv    = (const float*)d_in[2];
  const int*   sfc   = (const int*)  d_in[3];
  const float* probs = (const float*)d_in[4];
  const float* r1    = (const float*)d_in[5];
  const float* r2    = (const float*)d_in[6];
  float*  ws  = (float*)d_ws;
  float4* ws4 = (float4*)d_ws;
  float*  out = (float*)d_out;

  float*        acc   = ws;
  float4*       sb4   = ws4 + F4_SB;
  float4*       pts4  = ws4 + F4_PTS;
  half8*        pkV   = (half8*)(ws4 + F4_PKV);
  half8*        pkO   = (half8*)(ws4 + F4_PKO);
  unsigned int* minfU = (unsigned int*)(ws + WS_MINF);
  unsigned int* minrU = (unsigned int*)(ws + WS_MINR);
  const float*  minfF = ws + WS_MINF;
  const float*  minrF = ws + WS_MINR;

  k_init<<<NPTS/256, 256, 0, stream>>>((unsigned int*)ws);
  k_pack_verts<<<N_V/256, 256, 0, stream>>>(ov, pkV);
  k_obary_pack<<<N_F/256, 256, 0, stream>>>(ov, of, pkO);
  k_sbary<<<G_F/256, 256, 0, stream>>>(sv, sfc, sb4);
  k_pts<<<NPTS/256, 256, 0, stream>>>(sv, sfc, r1, r2, pts4);

  // fwd: 8192 queries (sb4) vs 16384 obary targets (512 tiles); 64 groups, ksplit=64
  k_min<<<dim3(16, 64), 256, 0, stream>>>(sb4, pkO, minfU, 512/64);
  // rev: 131072 queries (pts4) vs 16384 vert targets (512 tiles); 1024 groups, ksplit=8
  k_min<<<dim3(256, 8), 256, 0, stream>>>(pts4, pkV, minrU, 512/8);

  k_reduce<<<256, 256, 0, stream>>>(probs, minfF, minrF, acc);
  k_final<<<1, 1, 0, stream>>>(acc, out);
}

// Round 4
// 225.188 us; speedup vs baseline: 1.5799x; 1.5799x over previous
//
#include <hip/hip_runtime.h>
#include <math.h>

// Problem sizes (fixed by setup_inputs)
constexpr int N_V  = 16384;       // original vertices
constexpr int N_F  = 16384;       // original faces (targets for fwd)
constexpr int G_F  = 8192;        // simplified faces (queries for fwd)
constexpr int NS   = 16;          // samples per face
constexpr int NPTS = G_F * NS;    // 131072 sample points (queries for rev)

constexpr int MB = 2;             // 32-row query blocks per wave (64 queries/wave)

typedef _Float16 half8 __attribute__((ext_vector_type(8)));
typedef float    f32x16 __attribute__((ext_vector_type(16)));

// ---------------- workspace layout (float4 units first, 16B aligned) ----------
constexpr int F4_ACC   = 0;                    // 1  float4: accumulators
constexpr int F4_SB    = 1;                    // [G_F]  simp barycenters x,y,z,|b|^2
constexpr int F4_PTS   = F4_SB + G_F;          // [NPTS] sample points    x,y,z,|p|^2
constexpr int F4_PKV   = F4_PTS + NPTS;        // packed verts: 512 tiles * 64 * 16B
constexpr int F4_PKO   = F4_PKV + 32768;       // packed obary: 512 tiles * 64 * 16B
constexpr int F4_TOTAL = F4_PKO + 32768;
constexpr int WS_MINF  = F4_TOTAL * 4;         // [G_F]  fwd min d^2 (uint bits)
constexpr int WS_MINR  = WS_MINF + G_F;        // [NPTS] rev min d^2 (uint bits)

// Pack one target (x,y,z,sq) into B-fragment order (validated round 3, absmax=0):
// col n = lane&31, k = (lane>>5)*8 + j.
// k0-3 = hi(-2x,-2y,-2z,|v|^2), k4-7 = lo residuals, k8-11 = hi again, k12-15 = 0.
__device__ __forceinline__ void pack_target(float x, float y, float z, float sq,
                                            half8* __restrict__ pk, int tile, int n) {
  float ax = -2.0f*x, ay = -2.0f*y, az = -2.0f*z;
  _Float16 hx = (_Float16)ax, hy = (_Float16)ay, hz = (_Float16)az, hw = (_Float16)sq;
  _Float16 lx = (_Float16)(ax - (float)hx), ly = (_Float16)(ay - (float)hy);
  _Float16 lz = (_Float16)(az - (float)hz), lw = (_Float16)(sq - (float)hw);
  half8 h0; h0[0]=hx; h0[1]=hy; h0[2]=hz; h0[3]=hw; h0[4]=lx; h0[5]=ly; h0[6]=lz; h0[7]=lw;
  half8 h1; h1[0]=hx; h1[1]=hy; h1[2]=hz; h1[3]=hw;
  h1[4]=(_Float16)0.0f; h1[5]=(_Float16)0.0f; h1[6]=(_Float16)0.0f; h1[7]=(_Float16)0.0f;
  pk[(size_t)tile*64 + n]      = h0;
  pk[(size_t)tile*64 + 32 + n] = h1;
}

// Fused prep: accumulator init, min-array init, vertex pack, obary pack,
// sbary, sample points.  All index-disjoint tasks, one launch, NPTS threads.
__global__ void k_prep(const float* __restrict__ ov, const int* __restrict__ of,
                       const float* __restrict__ sv, const int* __restrict__ sf,
                       const float* __restrict__ r1, const float* __restrict__ r2,
                       unsigned int* __restrict__ ws, float4* __restrict__ ws4) {
  int i = blockIdx.x * blockDim.x + threadIdx.x;
  if (i < 4) ws[i] = 0u;                          // acc = 0.0f
  ws[WS_MINR + i] = 0x7f800000u;                  // +inf (grid == NPTS exactly)

  { // sample points (all i)
    int g = i >> 4;
    int a = sf[3*g], b = sf[3*g+1], c = sf[3*g+2];
    float sr = sqrtf(r1[i]);
    float u = 1.0f - sr;
    float v = sr * (1.0f - r2[i]);
    float w = sr * r2[i];
    float px = u*sv[3*a]   + v*sv[3*b]   + w*sv[3*c];
    float py = u*sv[3*a+1] + v*sv[3*b+1] + w*sv[3*c+1];
    float pz = u*sv[3*a+2] + v*sv[3*b+2] + w*sv[3*c+2];
    (ws4 + F4_PTS)[i] = make_float4(px, py, pz, fmaf(px, px, fmaf(py, py, pz*pz)));
  }
  if (i < G_F) { // simp barycenters (fwd queries) + minf init
    ws[WS_MINF + i] = 0x7f800000u;
    int a = sf[3*i], b = sf[3*i+1], c = sf[3*i+2];
    float x = (sv[3*a] + sv[3*b] + sv[3*c]) * (1.0f/3.0f);
    float y = (sv[3*a+1] + sv[3*b+1] + sv[3*c+1]) * (1.0f/3.0f);
    float z = (sv[3*a+2] + sv[3*b+2] + sv[3*c+2]) * (1.0f/3.0f);
    (ws4 + F4_SB)[i] = make_float4(x, y, z, fmaf(x, x, fmaf(y, y, z*z)));
  }
  if (i < N_V) { // packed vertices (rev targets)
    float x = ov[3*i], y = ov[3*i+1], z = ov[3*i+2];
    pack_target(x, y, z, fmaf(x, x, fmaf(y, y, z*z)),
                (half8*)(ws4 + F4_PKV), i >> 5, i & 31);
  }
  if (i < N_F) { // packed orig barycenters (fwd targets)
    int a = of[3*i], b = of[3*i+1], c = of[3*i+2];
    float x = (ov[3*a] + ov[3*b] + ov[3*c]) * (1.0f/3.0f);
    float y = (ov[3*a+1] + ov[3*b+1] + ov[3*c+1]) * (1.0f/3.0f);
    float z = (ov[3*a+2] + ov[3*b+2] + ov[3*c+2]) * (1.0f/3.0f);
    pack_target(x, y, z, fmaf(x, x, fmaf(y, y, z*z)),
                (half8*)(ws4 + F4_PKO), i >> 5, i & 31);
  }
}

// MFMA min-distance kernel.  Wave owns 64 queries (MB=2 x 32 rows), sweeps
// [blockIdx.y*tiles, +tiles) 32-target tiles, tile-unrolled x2 so the min
// stream is ONE v_min3_f32 per 128 pairs.  launch_bounds caps VGPR at 128
// so rm/d stay in VGPRs (round-3 failure mode: VGPR_Count=56 => AGPR churn).
__global__ __launch_bounds__(256, 4) void k_min(const float4* __restrict__ q4,
                                                const half8* __restrict__ pk,
                                                unsigned int* __restrict__ minU,
                                                int tiles) {
  int lane  = threadIdx.x & 63;
  int wave  = threadIdx.x >> 6;
  int half_ = lane >> 5;
  int m     = lane & 31;
  int qbase = (blockIdx.x * 4 + wave) * (32 * MB);
  int t0 = blockIdx.y * tiles;

  // A fragments (validated): A[m=lane&31][k=(lane>>5)*8+j]
  // half0: (p_hi,1, p_hi,1)   half1: (p_lo,0, 0,0,0,0)
  half8 afrag[MB];
  #pragma unroll
  for (int mb = 0; mb < MB; ++mb) {
    float4 q = q4[qbase + mb*32 + m];
    _Float16 hx = (_Float16)q.x, hy = (_Float16)q.y, hz = (_Float16)q.z;
    half8 a;
    if (half_ == 0) {
      a[0]=hx; a[1]=hy; a[2]=hz; a[3]=(_Float16)1.0f;
      a[4]=hx; a[5]=hy; a[6]=hz; a[7]=(_Float16)1.0f;
    } else {
      a[0]=(_Float16)(q.x-(float)hx); a[1]=(_Float16)(q.y-(float)hy);
      a[2]=(_Float16)(q.z-(float)hz); a[3]=(_Float16)0.0f;
      a[4]=(_Float16)0.0f; a[5]=(_Float16)0.0f; a[6]=(_Float16)0.0f; a[7]=(_Float16)0.0f;
    }
    afrag[mb] = a;
  }

  f32x16 zero;
  #pragma unroll
  for (int r = 0; r < 16; ++r) zero[r] = 0.0f;

  float inf = __uint_as_float(0x7f800000u);
  float rm[MB][16];
  #pragma unroll
  for (int mb = 0; mb < MB; ++mb)
    #pragma unroll
    for (int r = 0; r < 16; ++r) rm[mb][r] = inf;

  const half8* bp = pk + (size_t)t0*64 + lane;
  half8 bA = bp[0];
  half8 bB = bp[64];
  bp += 128;
  for (int t = 0; t < tiles; t += 2) {
    half8 cA = bA, cB = bB;
    if (t + 2 < tiles) { bA = bp[0]; bB = bp[64]; bp += 128; }
    f32x16 d0A = __builtin_amdgcn_mfma_f32_32x32x16_f16(afrag[0], cA, zero, 0, 0, 0);
    f32x16 d0B = __builtin_amdgcn_mfma_f32_32x32x16_f16(afrag[0], cB, zero, 0, 0, 0);
    f32x16 d1A = __builtin_amdgcn_mfma_f32_32x32x16_f16(afrag[1], cA, zero, 0, 0, 0);
    f32x16 d1B = __builtin_amdgcn_mfma_f32_32x32x16_f16(afrag[1], cB, zero, 0, 0, 0);
    #pragma unroll
    for (int r = 0; r < 16; ++r)
      rm[0][r] = fminf(fminf(rm[0][r], d0A[r]), d0B[r]);   // -> v_min3_f32
    #pragma unroll
    for (int r = 0; r < 16; ++r)
      rm[1][r] = fminf(fminf(rm[1][r], d1A[r]), d1B[r]);
  }

  // min across 32 target-columns (col = lane&31), then combine k-chunks.
  // C/D: col=lane&31, row=(reg&3)+8*(reg>>2)+4*(lane>>5)   (validated)
  #pragma unroll
  for (int mb = 0; mb < MB; ++mb) {
    #pragma unroll
    for (int r = 0; r < 16; ++r) {
      float v = rm[mb][r];
      v = fminf(v, __shfl_xor(v, 1, 64));
      v = fminf(v, __shfl_xor(v, 2, 64));
      v = fminf(v, __shfl_xor(v, 4, 64));
      v = fminf(v, __shfl_xor(v, 8, 64));
      v = fminf(v, __shfl_xor(v, 16, 64));
      if (m == 0) {
        int row  = (r & 3) + 8*(r >> 2) + 4*half_;
        int pidx = qbase + mb*32 + row;
        float d2 = fmaxf(q4[pidx].w + v, 0.0f);
        atomicMin(&minU[pidx], __float_as_uint(d2));
      }
    }
  }
}

__device__ __forceinline__ float waveSum(float v) {
  #pragma unroll
  for (int o = 32; o > 0; o >>= 1) v += __shfl_down(v, o, 64);
  return v;
}
__device__ __forceinline__ float waveMax(float v) {
  #pragma unroll
  for (int o = 32; o > 0; o >>= 1) v = fmaxf(v, __shfl_down(v, o, 64));
  return v;
}

__global__ void k_reduce(const float* __restrict__ probs, const float* __restrict__ minf,
                         const float* __restrict__ minr, float* __restrict__ acc) {
  int tid = blockIdx.x * blockDim.x + threadIdx.x;
  int stride = gridDim.x * blockDim.x;
  float sf = 0.0f, sr = 0.0f, mx = 0.0f;
  for (int i = tid; i < NPTS; i += stride) {
    float d = sqrtf(fmaxf(minr[i], 1e-12f));
    sr = fmaf(probs[i >> 4], d, sr);
    mx = fmaxf(mx, d);
    if (i < G_F) {
      float df = sqrtf(fmaxf(minf[i], 1e-12f));
      sf = fmaf(probs[i], df, sf);
      sf = fmaf(1e-4f, 1.0f - probs[i], sf);
    }
  }
  __shared__ float lf[4], lr[4], lm[4];
  int lane = threadIdx.x & 63, wid = threadIdx.x >> 6;
  sf = waveSum(sf); sr = waveSum(sr); mx = waveMax(mx);
  if (lane == 0) { lf[wid] = sf; lr[wid] = sr; lm[wid] = mx; }
  __syncthreads();
  if (wid == 0) {
    float a = (lane < 4) ? lf[lane] : 0.0f;
    float b = (lane < 4) ? lr[lane] : 0.0f;
    float c = (lane < 4) ? lm[lane] : 0.0f;
    a = waveSum(a); b = waveSum(b); c = waveMax(c);
    if (lane == 0) {
      atomicAdd(&acc[0], a);
      atomicAdd(&acc[1], b);
      atomicMax((unsigned int*)&acc[2], __float_as_uint(c));
    }
  }
}

__global__ void k_final(const float* __restrict__ acc, float* __restrict__ out) {
  float maxd = acc[2] + 1e-8f;
  out[0] = acc[0] + acc[1] * 0.1f / maxd;
}

extern "C" void kernel_launch(void* const* d_in, const int* in_sizes, int n_in,
                              void* d_out, int out_size, void* d_ws, size_t ws_size,
                              hipStream_t stream) {
  const float* ov    = (const float*)d_in[0];
  const int*   of    = (const int*)  d_in[1];
  const float* sv    = (const float*)d_in[2];
  const int*   sfc   = (const int*)  d_in[3];
  const float* probs = (const float*)d_in[4];
  const float* r1    = (const float*)d_in[5];
  const float* r2    = (const float*)d_in[6];
  float*  ws  = (float*)d_ws;
  float4* ws4 = (float4*)d_ws;
  float*  out = (float*)d_out;

  float*        acc   = ws;
  float4*       sb4   = ws4 + F4_SB;
  float4*       pts4  = ws4 + F4_PTS;
  half8*        pkV   = (half8*)(ws4 + F4_PKV);
  half8*        pkO   = (half8*)(ws4 + F4_PKO);
  unsigned int* minfU = (unsigned int*)(ws + WS_MINF);
  unsigned int* minrU = (unsigned int*)(ws + WS_MINR);
  const float*  minfF = ws + WS_MINF;
  const float*  minrF = ws + WS_MINR;

  k_prep<<<NPTS/256, 256, 0, stream>>>(ov, of, sv, sfc, r1, r2,
                                       (unsigned int*)ws, ws4);
  // fwd: 8192 queries vs 512 obary tiles; 128 groups -> 32 blocks.x, ksplit 32
  k_min<<<dim3(32, 32), 256, 0, stream>>>(sb4, pkO, minfU, 512/32);
  // rev: 131072 queries vs 512 vert tiles; 2048 groups -> 512 blocks.x, ksplit 8
  k_min<<<dim3(512, 8), 256, 0, stream>>>(pts4, pkV, minrU, 512/8);
  k_reduce<<<256, 256, 0, stream>>>(probs, minfF, minrF, acc);
  k_final<<<1, 1, 0, stream>>>(acc, out);
}

// Round 5
// 202.548 us; speedup vs baseline: 1.7565x; 1.1118x over previous
//
#include <hip/hip_runtime.h>
#include <math.h>

// Problem sizes (fixed by setup_inputs)
constexpr int N_V  = 16384;       // original vertices
constexpr int N_F  = 16384;       // original faces (targets for fwd)
constexpr int G_F  = 8192;        // simplified faces (queries for fwd)
constexpr int NS   = 16;          // samples per face
constexpr int NPTS = G_F * NS;    // 131072 sample points (queries for rev)

constexpr int MB    = 2;          // 32-row query blocks per wave (64 queries/wave)
constexpr int TILES = 32;         // B-tiles staged per block (32 KB LDS)
constexpr int KS    = 16;         // k-split: 512 tiles / 32

typedef _Float16 half8 __attribute__((ext_vector_type(8)));
typedef float    f32x16 __attribute__((ext_vector_type(16)));

// ---------------- workspace layout (float4 units first, 16B aligned) ----------
constexpr int F4_ACC   = 0;                    // 1  float4: accumulators
constexpr int F4_SB    = 1;                    // [G_F]  simp barycenters x,y,z,|b|^2
constexpr int F4_PTS   = F4_SB + G_F;          // [NPTS] sample points    x,y,z,|p|^2
constexpr int F4_PKV   = F4_PTS + NPTS;        // packed verts: 512 tiles * 64 * 16B
constexpr int F4_PKO   = F4_PKV + 32768;       // packed obary: 512 tiles * 64 * 16B
constexpr int F4_TOTAL = F4_PKO + 32768;
constexpr int WS_MINF  = F4_TOTAL * 4;         // [G_F]  fwd min d^2 (uint bits)
constexpr int WS_MINR  = WS_MINF + G_F;        // [NPTS] rev min d^2 (uint bits)

// Pack one target (x,y,z,sq) into B-fragment order (validated: absmax=0):
// col n = lane&31, k = (lane>>5)*8 + j.
// k0-3 = hi(-2x,-2y,-2z,|v|^2), k4-7 = lo residuals, k8-11 = hi again, k12-15 = 0.
__device__ __forceinline__ void pack_target(float x, float y, float z, float sq,
                                            half8* __restrict__ pk, int tile, int n) {
  float ax = -2.0f*x, ay = -2.0f*y, az = -2.0f*z;
  _Float16 hx = (_Float16)ax, hy = (_Float16)ay, hz = (_Float16)az, hw = (_Float16)sq;
  _Float16 lx = (_Float16)(ax - (float)hx), ly = (_Float16)(ay - (float)hy);
  _Float16 lz = (_Float16)(az - (float)hz), lw = (_Float16)(sq - (float)hw);
  half8 h0; h0[0]=hx; h0[1]=hy; h0[2]=hz; h0[3]=hw; h0[4]=lx; h0[5]=ly; h0[6]=lz; h0[7]=lw;
  half8 h1; h1[0]=hx; h1[1]=hy; h1[2]=hz; h1[3]=hw;
  h1[4]=(_Float16)0.0f; h1[5]=(_Float16)0.0f; h1[6]=(_Float16)0.0f; h1[7]=(_Float16)0.0f;
  pk[(size_t)tile*64 + n]      = h0;
  pk[(size_t)tile*64 + 32 + n] = h1;
}

// Fused prep.  Grid = NPTS threads.  Sample points are generated one-thread-
// per-FACE (16 pts each) so the 9 vertex gathers happen once per face, not 16x.
__global__ void k_prep(const float* __restrict__ ov, const int* __restrict__ of,
                       const float* __restrict__ sv, const int* __restrict__ sf,
                       const float* __restrict__ r1, const float* __restrict__ r2,
                       unsigned int* __restrict__ ws, float4* __restrict__ ws4) {
  int i = blockIdx.x * blockDim.x + threadIdx.x;
  if (i < 4) ws[i] = 0u;                          // acc = 0.0f
  ws[WS_MINR + i] = 0x7f800000u;                  // +inf (grid == NPTS exactly)

  if (i < G_F) { // per-face: minf init, simp barycenter, 16 sample points
    ws[WS_MINF + i] = 0x7f800000u;
    int a = sf[3*i], b = sf[3*i+1], c = sf[3*i+2];
    float axv = sv[3*a], ayv = sv[3*a+1], azv = sv[3*a+2];
    float bxv = sv[3*b], byv = sv[3*b+1], bzv = sv[3*b+2];
    float cxv = sv[3*c], cyv = sv[3*c+1], czv = sv[3*c+2];
    float x = (axv+bxv+cxv)*(1.0f/3.0f);
    float y = (ayv+byv+cyv)*(1.0f/3.0f);
    float z = (azv+bzv+czv)*(1.0f/3.0f);
    (ws4 + F4_SB)[i] = make_float4(x, y, z, fmaf(x, x, fmaf(y, y, z*z)));

    const float4* R1 = (const float4*)r1;
    const float4* R2 = (const float4*)r2;
    float4* P = ws4 + F4_PTS + (size_t)i*16;
    #pragma unroll
    for (int j = 0; j < 4; ++j) {
      float4 q1 = R1[i*4 + j];
      float4 q2 = R2[i*4 + j];
      float r1s[4] = {q1.x, q1.y, q1.z, q1.w};
      float r2s[4] = {q2.x, q2.y, q2.z, q2.w};
      #pragma unroll
      for (int s = 0; s < 4; ++s) {
        float sr = sqrtf(r1s[s]);
        float u = 1.0f - sr;
        float v = sr * (1.0f - r2s[s]);
        float w = sr * r2s[s];
        float px = u*axv + v*bxv + w*cxv;
        float py = u*ayv + v*byv + w*cyv;
        float pz = u*azv + v*bzv + w*czv;
        P[j*4 + s] = make_float4(px, py, pz, fmaf(px, px, fmaf(py, py, pz*pz)));
      }
    }
  }
  if (i < N_V) { // packed vertices (rev targets)
    float x = ov[3*i], y = ov[3*i+1], z = ov[3*i+2];
    pack_target(x, y, z, fmaf(x, x, fmaf(y, y, z*z)),
                (half8*)(ws4 + F4_PKV), i >> 5, i & 31);
  }
  if (i < N_F) { // packed orig barycenters (fwd targets)
    int a = of[3*i], b = of[3*i+1], c = of[3*i+2];
    float x = (ov[3*a] + ov[3*b] + ov[3*c]) * (1.0f/3.0f);
    float y = (ov[3*a+1] + ov[3*b+1] + ov[3*c+1]) * (1.0f/3.0f);
    float z = (ov[3*a+2] + ov[3*b+2] + ov[3*c+2]) * (1.0f/3.0f);
    pack_target(x, y, z, fmaf(x, x, fmaf(y, y, z*z)),
                (half8*)(ws4 + F4_PKO), i >> 5, i & 31);
  }
}

// MFMA min-distance kernel, LDS-staged.
// Block = 256 queries (4 waves x 64).  All 32 B-tiles (32 KB) for this k-chunk
// are staged into LDS once via async global_load_lds (width 16), ONE barrier,
// then swept with ds_read_b128 + one 32x32x16 MFMA per 32q x 32t tile.
// mb groups separated by sched_barrier(0) so at most 2 MFMA result sets (32
// VGPRs) are live -> no AGPR churn (round-3/4 failure: VGPR_Count 52 + accvgpr).
__global__ __launch_bounds__(256, 4) void k_min(const float4* __restrict__ q4,
                                                const half8* __restrict__ pk,
                                                unsigned int* __restrict__ minU) {
  __shared__ half8 sB[TILES * 64];   // 32 KB
  int lane  = threadIdx.x & 63;
  int wave  = threadIdx.x >> 6;
  int half_ = lane >> 5;
  int m     = lane & 31;
  int qbase = blockIdx.x * 256 + wave * (32 * MB);
  int t0 = blockIdx.y * TILES;

  // async stage: wave w loads tiles w, w+4, ..., w+28 (1 KB each, lane*16B)
  const half8* src = pk + (size_t)(t0 + wave) * 64 + lane;
  #pragma unroll
  for (int j = 0; j < TILES/4; ++j) {
    __builtin_amdgcn_global_load_lds(
        (const __attribute__((address_space(1))) unsigned int*)(src + (size_t)j*256),
        (__attribute__((address_space(3))) unsigned int*)&sB[(wave + 4*j) * 64],
        16, 0, 0);
  }

  // A fragments (validated): A[m=lane&31][k=(lane>>5)*8+j]
  // half0: (p_hi,1, p_hi,1)   half1: (p_lo,0, 0,0,0,0)
  half8 afrag[MB];
  float psq[MB];
  #pragma unroll
  for (int mb = 0; mb < MB; ++mb) {
    float4 q = q4[qbase + mb*32 + m];
    psq[mb] = q.w;
    _Float16 hx = (_Float16)q.x, hy = (_Float16)q.y, hz = (_Float16)q.z;
    half8 a;
    if (half_ == 0) {
      a[0]=hx; a[1]=hy; a[2]=hz; a[3]=(_Float16)1.0f;
      a[4]=hx; a[5]=hy; a[6]=hz; a[7]=(_Float16)1.0f;
    } else {
      a[0]=(_Float16)(q.x-(float)hx); a[1]=(_Float16)(q.y-(float)hy);
      a[2]=(_Float16)(q.z-(float)hz); a[3]=(_Float16)0.0f;
      a[4]=(_Float16)0.0f; a[5]=(_Float16)0.0f; a[6]=(_Float16)0.0f; a[7]=(_Float16)0.0f;
    }
    afrag[mb] = a;
  }

  f32x16 zero;
  #pragma unroll
  for (int r = 0; r < 16; ++r) zero[r] = 0.0f;

  float inf = __uint_as_float(0x7f800000u);
  float rm[MB][16];
  #pragma unroll
  for (int mb = 0; mb < MB; ++mb)
    #pragma unroll
    for (int r = 0; r < 16; ++r) rm[mb][r] = inf;

  __syncthreads();   // compiler drains vmcnt(0) -> all LDS tiles resident

  for (int t = 0; t < TILES; t += 2) {
    half8 cA = sB[t*64 + lane];        // ds_read_b128, conflict-free
    half8 cB = sB[t*64 + 64 + lane];
    f32x16 dA = __builtin_amdgcn_mfma_f32_32x32x16_f16(afrag[0], cA, zero, 0, 0, 0);
    f32x16 dB = __builtin_amdgcn_mfma_f32_32x32x16_f16(afrag[0], cB, zero, 0, 0, 0);
    #pragma unroll
    for (int r = 0; r < 16; ++r)
      rm[0][r] = fminf(fminf(rm[0][r], dA[r]), dB[r]);   // -> v_min3_f32
    __builtin_amdgcn_sched_barrier(0);                   // cap d-liveness at 32
    f32x16 eA = __builtin_amdgcn_mfma_f32_32x32x16_f16(afrag[1], cA, zero, 0, 0, 0);
    f32x16 eB = __builtin_amdgcn_mfma_f32_32x32x16_f16(afrag[1], cB, zero, 0, 0, 0);
    #pragma unroll
    for (int r = 0; r < 16; ++r)
      rm[1][r] = fminf(fminf(rm[1][r], eA[r]), eB[r]);
  }

  // min across 32 target-columns; write from lane m == row (no q4 reload).
  // C/D: col=lane&31, row=(reg&3)+8*(reg>>2)+4*(lane>>5)   (validated)
  #pragma unroll
  for (int mb = 0; mb < MB; ++mb) {
    #pragma unroll
    for (int r = 0; r < 16; ++r) {
      float v = rm[mb][r];
      v = fminf(v, __shfl_xor(v, 1, 64));
      v = fminf(v, __shfl_xor(v, 2, 64));
      v = fminf(v, __shfl_xor(v, 4, 64));
      v = fminf(v, __shfl_xor(v, 8, 64));
      v = fminf(v, __shfl_xor(v, 16, 64));
      int row = (r & 3) + 8*(r >> 2) + 4*half_;
      if (m == row) {
        float d2 = fmaxf(psq[mb] + v, 0.0f);
        atomicMin(&minU[qbase + mb*32 + m], __float_as_uint(d2));
      }
    }
  }
}

__device__ __forceinline__ float waveSum(float v) {
  #pragma unroll
  for (int o = 32; o > 0; o >>= 1) v += __shfl_down(v, o, 64);
  return v;
}
__device__ __forceinline__ float waveMax(float v) {
  #pragma unroll
  for (int o = 32; o > 0; o >>= 1) v = fmaxf(v, __shfl_down(v, o, 64));
  return v;
}

__global__ void k_reduce(const float* __restrict__ probs, const float* __restrict__ minf,
                         const float* __restrict__ minr, float* __restrict__ acc) {
  int tid = blockIdx.x * blockDim.x + threadIdx.x;
  int stride = gridDim.x * blockDim.x;
  float sf = 0.0f, sr = 0.0f, mx = 0.0f;
  for (int i = tid; i < NPTS; i += stride) {
    float d = sqrtf(fmaxf(minr[i], 1e-12f));
    sr = fmaf(probs[i >> 4], d, sr);
    mx = fmaxf(mx, d);
    if (i < G_F) {
      float df = sqrtf(fmaxf(minf[i], 1e-12f));
      sf = fmaf(probs[i], df, sf);
      sf = fmaf(1e-4f, 1.0f - probs[i], sf);
    }
  }
  __shared__ float lf[4], lr[4], lm[4];
  int lane = threadIdx.x & 63, wid = threadIdx.x >> 6;
  sf = waveSum(sf); sr = waveSum(sr); mx = waveMax(mx);
  if (lane == 0) { lf[wid] = sf; lr[wid] = sr; lm[wid] = mx; }
  __syncthreads();
  if (wid == 0) {
    float a = (lane < 4) ? lf[lane] : 0.0f;
    float b = (lane < 4) ? lr[lane] : 0.0f;
    float c = (lane < 4) ? lm[lane] : 0.0f;
    a = waveSum(a); b = waveSum(b); c = waveMax(c);
    if (lane == 0) {
      atomicAdd(&acc[0], a);
      atomicAdd(&acc[1], b);
      atomicMax((unsigned int*)&acc[2], __float_as_uint(c));
    }
  }
}

__global__ void k_final(const float* __restrict__ acc, float* __restrict__ out) {
  float maxd = acc[2] + 1e-8f;
  out[0] = acc[0] + acc[1] * 0.1f / maxd;
}

extern "C" void kernel_launch(void* const* d_in, const int* in_sizes, int n_in,
                              void* d_out, int out_size, void* d_ws, size_t ws_size,
                              hipStream_t stream) {
  const float* ov    = (const float*)d_in[0];
  const int*   of    = (const int*)  d_in[1];
  const float* sv    = (const float*)d_in[2];
  const int*   sfc   = (const int*)  d_in[3];
  const float* probs = (const float*)d_in[4];
  const float* r1    = (const float*)d_in[5];
  const float* r2    = (const float*)d_in[6];
  float*  ws  = (float*)d_ws;
  float4* ws4 = (float4*)d_ws;
  float*  out = (float*)d_out;

  float*        acc   = ws;
  float4*       sb4   = ws4 + F4_SB;
  float4*       pts4  = ws4 + F4_PTS;
  half8*        pkV   = (half8*)(ws4 + F4_PKV);
  half8*        pkO   = (half8*)(ws4 + F4_PKO);
  unsigned int* minfU = (unsigned int*)(ws + WS_MINF);
  unsigned int* minrU = (unsigned int*)(ws + WS_MINR);
  const float*  minfF = ws + WS_MINF;
  const float*  minrF = ws + WS_MINR;

  k_prep<<<NPTS/256, 256, 0, stream>>>(ov, of, sv, sfc, r1, r2,
                                       (unsigned int*)ws, ws4);
  // fwd: 8192 queries, 512 obary tiles; 32 blocks.x x 16 k-chunks
  k_min<<<dim3(G_F/256, KS), 256, 0, stream>>>(sb4, pkO, minfU);
  // rev: 131072 queries, 512 vert tiles; 512 blocks.x x 16 k-chunks
  k_min<<<dim3(NPTS/256, KS), 256, 0, stream>>>(pts4, pkV, minrU);
  k_reduce<<<256, 256, 0, stream>>>(probs, minfF, minrF, acc);
  k_final<<<1, 1, 0, stream>>>(acc, out);
}

// Round 7
// 183.314 us; speedup vs baseline: 1.9409x; 1.1049x over previous
//
#include <hip/hip_runtime.h>
#include <math.h>

// Problem sizes (fixed by setup_inputs)
constexpr int N_V  = 16384;       // original vertices
constexpr int N_F  = 16384;       // original faces (targets for fwd)
constexpr int G_F  = 8192;        // simplified faces (queries for fwd)
constexpr int NS   = 16;          // samples per face
constexpr int NPTS = G_F * NS;    // 131072 sample points (queries for rev)

constexpr int MB    = 2;          // 32-row query blocks per wave (64 queries/wave)
constexpr int TILES = 32;         // B-tiles staged per LDS chunk (32 KB)

typedef _Float16 half8 __attribute__((ext_vector_type(8)));
typedef float    f32x16 __attribute__((ext_vector_type(16)));

// ---------------- workspace layout (float4 units first, 16B aligned) ----------
constexpr int F4_ACC   = 0;                    // 1  float4: accumulators
constexpr int F4_SB    = 1;                    // [G_F]  simp barycenters x,y,z,|b|^2
constexpr int F4_PTS   = F4_SB + G_F;          // [NPTS] sample points    x,y,z,|p|^2
constexpr int F4_PKV   = F4_PTS + NPTS;        // packed verts: 512 tiles * 64 * 16B
constexpr int F4_PKO   = F4_PKV + 32768;       // packed obary: 512 tiles * 64 * 16B
constexpr int F4_TOTAL = F4_PKO + 32768;
constexpr int WS_MINF  = F4_TOTAL * 4;         // [G_F]  fwd min d^2 (uint bits)
constexpr int WS_MINR  = WS_MINF + G_F;        // [NPTS] rev min d^2 (uint bits)

// 4 MFMAs of one tile-pair in ONE asm block, dsts FORCED to arch VGPRs
// (rounds 3-5: builtin dst class -> AGPR churn).  Round-6 failure: inline asm
// is opaque to the compiler's XDL hazard recognizer, so the MFMA-write ->
// VALU-read wait states must be inserted manually: 6 x s_nop 7 = 48 cycles
// covers the ~34-cycle worst case for the last MFMA; earlier ones get extra
// spacing from the subsequent issues.  Nops cost only this wave's issue slot.
__device__ __forceinline__ void mfma4(half8 a0, half8 a1, half8 cA, half8 cB,
                                      f32x16& d0A, f32x16& d0B,
                                      f32x16& d1A, f32x16& d1B) {
  asm("v_mfma_f32_32x32x16_f16 %0, %4, %6, 0\n\t"
      "v_mfma_f32_32x32x16_f16 %1, %4, %7, 0\n\t"
      "v_mfma_f32_32x32x16_f16 %2, %5, %6, 0\n\t"
      "v_mfma_f32_32x32x16_f16 %3, %5, %7, 0\n\t"
      "s_nop 7\n\t"
      "s_nop 7\n\t"
      "s_nop 7\n\t"
      "s_nop 7\n\t"
      "s_nop 7\n\t"
      "s_nop 7"
      : "=&v"(d0A), "=&v"(d0B), "=&v"(d1A), "=&v"(d1B)
      : "v"(a0), "v"(a1), "v"(cA), "v"(cB));
}

// Pack one target (x,y,z,sq) into B-fragment order (validated: absmax=0):
// col n = lane&31, k = (lane>>5)*8 + j.
// k0-3 = hi(-2x,-2y,-2z,|v|^2), k4-7 = lo residuals, k8-11 = hi again, k12-15 = 0.
__device__ __forceinline__ void pack_target(float x, float y, float z, float sq,
                                            half8* __restrict__ pk, int tile, int n) {
  float ax = -2.0f*x, ay = -2.0f*y, az = -2.0f*z;
  _Float16 hx = (_Float16)ax, hy = (_Float16)ay, hz = (_Float16)az, hw = (_Float16)sq;
  _Float16 lx = (_Float16)(ax - (float)hx), ly = (_Float16)(ay - (float)hy);
  _Float16 lz = (_Float16)(az - (float)hz), lw = (_Float16)(sq - (float)hw);
  half8 h0; h0[0]=hx; h0[1]=hy; h0[2]=hz; h0[3]=hw; h0[4]=lx; h0[5]=ly; h0[6]=lz; h0[7]=lw;
  half8 h1; h1[0]=hx; h1[1]=hy; h1[2]=hz; h1[3]=hw;
  h1[4]=(_Float16)0.0f; h1[5]=(_Float16)0.0f; h1[6]=(_Float16)0.0f; h1[7]=(_Float16)0.0f;
  pk[(size_t)tile*64 + n]      = h0;
  pk[(size_t)tile*64 + 32 + n] = h1;
}

// Fused prep, one thread per sample point.
__global__ void k_prep(const float* __restrict__ ov, const int* __restrict__ of,
                       const float* __restrict__ sv, const int* __restrict__ sf,
                       const float* __restrict__ r1, const float* __restrict__ r2,
                       unsigned int* __restrict__ ws, float4* __restrict__ ws4) {
  int i = blockIdx.x * blockDim.x + threadIdx.x;
  if (i < 4) ws[i] = 0u;                          // acc = 0.0f
  ws[WS_MINR + i] = 0x7f800000u;                  // +inf (grid == NPTS exactly)

  { // sample point i (face verts are 48 KB total -> L1/L2-hot gathers)
    int g = i >> 4;
    int a = sf[3*g], b = sf[3*g+1], c = sf[3*g+2];
    float sr = sqrtf(r1[i]);
    float u = 1.0f - sr;
    float v = sr * (1.0f - r2[i]);
    float w = sr * r2[i];
    float px = u*sv[3*a]   + v*sv[3*b]   + w*sv[3*c];
    float py = u*sv[3*a+1] + v*sv[3*b+1] + w*sv[3*c+1];
    float pz = u*sv[3*a+2] + v*sv[3*b+2] + w*sv[3*c+2];
    (ws4 + F4_PTS)[i] = make_float4(px, py, pz, fmaf(px, px, fmaf(py, py, pz*pz)));
  }
  if (i < G_F) { // simp barycenter (fwd query) + minf init
    ws[WS_MINF + i] = 0x7f800000u;
    int a = sf[3*i], b = sf[3*i+1], c = sf[3*i+2];
    float x = (sv[3*a] + sv[3*b] + sv[3*c]) * (1.0f/3.0f);
    float y = (sv[3*a+1] + sv[3*b+1] + sv[3*c+1]) * (1.0f/3.0f);
    float z = (sv[3*a+2] + sv[3*b+2] + sv[3*c+2]) * (1.0f/3.0f);
    (ws4 + F4_SB)[i] = make_float4(x, y, z, fmaf(x, x, fmaf(y, y, z*z)));
  }
  if (i < N_V) { // packed vertices (rev targets)
    float x = ov[3*i], y = ov[3*i+1], z = ov[3*i+2];
    pack_target(x, y, z, fmaf(x, x, fmaf(y, y, z*z)),
                (half8*)(ws4 + F4_PKV), i >> 5, i & 31);
  }
  if (i < N_F) { // packed orig barycenters (fwd targets)
    int a = of[3*i], b = of[3*i+1], c = of[3*i+2];
    float x = (ov[3*a] + ov[3*b] + ov[3*c]) * (1.0f/3.0f);
    float y = (ov[3*a+1] + ov[3*b+1] + ov[3*c+1]) * (1.0f/3.0f);
    float z = (ov[3*a+2] + ov[3*b+2] + ov[3*c+2]) * (1.0f/3.0f);
    pack_target(x, y, z, fmaf(x, x, fmaf(y, y, z*z)),
                (half8*)(ws4 + F4_PKO), i >> 5, i & 31);
  }
}

// MFMA min-distance kernel, LDS-staged, VGPR-dst MFMA via hazard-padded asm.
// Block = 256 queries (4 waves x 64).  Sweeps nchunks chunks of 32 B-tiles;
// each chunk async-staged to LDS (global_load_lds w16), one barrier, then
// ds_read_b128 + mfma4 + 32 v_min3_f32 per tile-pair.
// launch_bounds (256,3): VGPR cap 168 — explicit liveness is ~125, must not
// spill rm to scratch (12 waves/CU is enough: VALU demand ~50% of MFMA time).
__global__ __launch_bounds__(256, 3) void k_min(const float4* __restrict__ q4,
                                                const half8* __restrict__ pk,
                                                unsigned int* __restrict__ minU,
                                                int nchunks) {
  __shared__ half8 sB[TILES * 64];   // 32 KB
  int lane  = threadIdx.x & 63;
  int wave  = threadIdx.x >> 6;
  int half_ = lane >> 5;
  int m     = lane & 31;
  int qbase = blockIdx.x * 256 + wave * (32 * MB);
  int tbase = blockIdx.y * nchunks * TILES;

  // A fragments (validated): A[m=lane&31][k=(lane>>5)*8+j]
  // half0: (p_hi,1, p_hi,1)   half1: (p_lo,0, 0,0,0,0)
  half8 afrag[MB];
  float psq[MB];
  #pragma unroll
  for (int mb = 0; mb < MB; ++mb) {
    float4 q = q4[qbase + mb*32 + m];
    psq[mb] = q.w;
    _Float16 hx = (_Float16)q.x, hy = (_Float16)q.y, hz = (_Float16)q.z;
    half8 a;
    if (half_ == 0) {
      a[0]=hx; a[1]=hy; a[2]=hz; a[3]=(_Float16)1.0f;
      a[4]=hx; a[5]=hy; a[6]=hz; a[7]=(_Float16)1.0f;
    } else {
      a[0]=(_Float16)(q.x-(float)hx); a[1]=(_Float16)(q.y-(float)hy);
      a[2]=(_Float16)(q.z-(float)hz); a[3]=(_Float16)0.0f;
      a[4]=(_Float16)0.0f; a[5]=(_Float16)0.0f; a[6]=(_Float16)0.0f; a[7]=(_Float16)0.0f;
    }
    afrag[mb] = a;
  }

  float inf = __uint_as_float(0x7f800000u);
  float rm[MB][16];
  #pragma unroll
  for (int mb = 0; mb < MB; ++mb)
    #pragma unroll
    for (int r = 0; r < 16; ++r) rm[mb][r] = inf;

  for (int ch = 0; ch < nchunks; ++ch) {
    int t0 = tbase + ch * TILES;
    if (ch > 0) __syncthreads();   // prior sweep done before overwriting sB
    // async stage: wave w loads tiles w, w+4, ..., w+28 (1 KB each, lane*16B)
    const half8* src = pk + (size_t)(t0 + wave) * 64 + lane;
    #pragma unroll
    for (int j = 0; j < TILES/4; ++j) {
      __builtin_amdgcn_global_load_lds(
          (const __attribute__((address_space(1))) unsigned int*)(src + (size_t)j*256),
          (__attribute__((address_space(3))) unsigned int*)&sB[(wave + 4*j) * 64],
          16, 0, 0);
    }
    __syncthreads();               // vmcnt(0) drained -> tiles resident

    for (int t = 0; t < TILES; t += 2) {
      half8 cA = sB[t*64 + lane];        // ds_read_b128
      half8 cB = sB[t*64 + 64 + lane];
      f32x16 dA, dB, eA, eB;
      mfma4(afrag[0], afrag[1], cA, cB, dA, dB, eA, eB);
      #pragma unroll
      for (int r = 0; r < 16; ++r)
        rm[0][r] = fminf(fminf(rm[0][r], dA[r]), dB[r]);   // v_min3_f32, pure VGPR
      #pragma unroll
      for (int r = 0; r < 16; ++r)
        rm[1][r] = fminf(fminf(rm[1][r], eA[r]), eB[r]);
    }
  }

  // min across 32 target-columns; write from lane m == row (no q4 reload).
  // C/D: col=lane&31, row=(reg&3)+8*(reg>>2)+4*(lane>>5)   (validated)
  #pragma unroll
  for (int mb = 0; mb < MB; ++mb) {
    #pragma unroll
    for (int r = 0; r < 16; ++r) {
      float v = rm[mb][r];
      v = fminf(v, __shfl_xor(v, 1, 64));
      v = fminf(v, __shfl_xor(v, 2, 64));
      v = fminf(v, __shfl_xor(v, 4, 64));
      v = fminf(v, __shfl_xor(v, 8, 64));
      v = fminf(v, __shfl_xor(v, 16, 64));
      int row = (r & 3) + 8*(r >> 2) + 4*half_;
      if (m == row) {
        float d2 = fmaxf(psq[mb] + v, 0.0f);
        atomicMin(&minU[qbase + mb*32 + m], __float_as_uint(d2));
      }
    }
  }
}

__device__ __forceinline__ float waveSum(float v) {
  #pragma unroll
  for (int o = 32; o > 0; o >>= 1) v += __shfl_down(v, o, 64);
  return v;
}
__device__ __forceinline__ float waveMax(float v) {
  #pragma unroll
  for (int o = 32; o > 0; o >>= 1) v = fmaxf(v, __shfl_down(v, o, 64));
  return v;
}

__global__ void k_reduce(const float* __restrict__ probs, const float* __restrict__ minf,
                         const float* __restrict__ minr, float* __restrict__ acc) {
  int tid = blockIdx.x * blockDim.x + threadIdx.x;
  int stride = gridDim.x * blockDim.x;
  float sf = 0.0f, sr = 0.0f, mx = 0.0f;
  for (int i = tid; i < NPTS; i += stride) {
    float d = sqrtf(fmaxf(minr[i], 1e-12f));
    sr = fmaf(probs[i >> 4], d, sr);
    mx = fmaxf(mx, d);
    if (i < G_F) {
      float df = sqrtf(fmaxf(minf[i], 1e-12f));
      sf = fmaf(probs[i], df, sf);
      sf = fmaf(1e-4f, 1.0f - probs[i], sf);
    }
  }
  __shared__ float lf[4], lr[4], lm[4];
  int lane = threadIdx.x & 63, wid = threadIdx.x >> 6;
  sf = waveSum(sf); sr = waveSum(sr); mx = waveMax(mx);
  if (lane == 0) { lf[wid] = sf; lr[wid] = sr; lm[wid] = mx; }
  __syncthreads();
  if (wid == 0) {
    float a = (lane < 4) ? lf[lane] : 0.0f;
    float b = (lane < 4) ? lr[lane] : 0.0f;
    float c = (lane < 4) ? lm[lane] : 0.0f;
    a = waveSum(a); b = waveSum(b); c = waveMax(c);
    if (lane == 0) {
      atomicAdd(&acc[0], a);
      atomicAdd(&acc[1], b);
      atomicMax((unsigned int*)&acc[2], __float_as_uint(c));
    }
  }
}

__global__ void k_final(const float* __restrict__ acc, float* __restrict__ out) {
  float maxd = acc[2] + 1e-8f;
  out[0] = acc[0] + acc[1] * 0.1f / maxd;
}

extern "C" void kernel_launch(void* const* d_in, const int* in_sizes, int n_in,
                              void* d_out, int out_size, void* d_ws, size_t ws_size,
                              hipStream_t stream) {
  const float* ov    = (const float*)d_in[0];
  const int*   of    = (const int*)  d_in[1];
  const float* sv    = (const float*)d_in[2];
  const int*   sfc   = (const int*)  d_in[3];
  const float* probs = (const float*)d_in[4];
  const float* r1    = (const float*)d_in[5];
  const float* r2    = (const float*)d_in[6];
  float*  ws  = (float*)d_ws;
  float4* ws4 = (float4*)d_ws;
  float*  out = (float*)d_out;

  float*        acc   = ws;
  float4*       sb4   = ws4 + F4_SB;
  float4*       pts4  = ws4 + F4_PTS;
  half8*        pkV   = (half8*)(ws4 + F4_PKV);
  half8*        pkO   = (half8*)(ws4 + F4_PKO);
  unsigned int* minfU = (unsigned int*)(ws + WS_MINF);
  unsigned int* minrU = (unsigned int*)(ws + WS_MINR);
  const float*  minfF = ws + WS_MINF;
  const float*  minrF = ws + WS_MINR;

  k_prep<<<NPTS/256, 256, 0, stream>>>(ov, of, sv, sfc, r1, r2,
                                       (unsigned int*)ws, ws4);
  // fwd: 8192 queries, 512 obary tiles; 32 x 16 blocks, 1 chunk each
  k_min<<<dim3(G_F/256, 16), 256, 0, stream>>>(sb4, pkO, minfU, 1);
  // rev: 131072 queries, 512 vert tiles; 512 x 8 blocks, 2 chunks each
  k_min<<<dim3(NPTS/256, 8), 256, 0, stream>>>(pts4, pkV, minrU, 2);
  k_reduce<<<256, 256, 0, stream>>>(probs, minfF, minrF, acc);
  k_final<<<1, 1, 0, stream>>>(acc, out);
}